// Round 1
// baseline (214.857 us; speedup 1.0000x reference)
//
#include <hip/hip_runtime.h>
#include <math.h>

#define NB 4096
#define ND 128

#define TI 16          // rows per block
#define TJ 512         // j-tile
#define DC 32          // d-chunk staged per pass
#define MI 4           // micro-tile rows per thread
#define NJ 4           // micro-tile cols per thread
#define NTHREADS 512   // trows(4) x tcols(128)
#define FJ_STRIDE 36   // DC + 4 dwords pad (keeps 16B align, kills bank conflicts)
#define FI_STRIDE 132  // ND + 4 dwords pad

// ---------------- row L2-normalize: fn = f / max(||f||, 1e-12) ----------------
__global__ void rownorm_kernel(const float* __restrict__ f, float* __restrict__ fn) {
    const int row  = blockIdx.x;
    const int lane = threadIdx.x;  // 64 lanes, 2 floats each
    float2 v = reinterpret_cast<const float2*>(f + (size_t)row * ND)[lane];
    float ss = v.x * v.x + v.y * v.y;
#pragma unroll
    for (int off = 1; off < 64; off <<= 1)
        ss += __shfl_xor(ss, off, 64);
    const float inv = 1.0f / fmaxf(sqrtf(ss), 1e-12f);
    float2 o; o.x = v.x * inv; o.y = v.y * inv;
    reinterpret_cast<float2*>(fn + (size_t)row * ND)[lane] = o;
}

// ---------------- main: fused sim-GEMM + online softmax stats + loss ----------
__global__ __launch_bounds__(NTHREADS) void supcon_kernel(
    const float* __restrict__ fn, const int* __restrict__ labels,
    float* __restrict__ out)
{
    __shared__ float fi[TI][FI_STRIDE];   // 16*132*4  = 8448 B
    __shared__ float fj[TJ][FJ_STRIDE];   // 512*36*4  = 73728 B
    __shared__ float red[8][MI][3];       // per-wave partials

    const int t  = threadIdx.x;
    const int ib = blockIdx.x * TI;
    const int tr = t >> 7;    // 0..3  (row group; uniform within a wave)
    const int tc = t & 127;   // 0..127 (col group; consecutive within a wave)

    // stage fi: 16 rows x 128 d, one float4 per thread
    {
        const int row = t >> 5;          // 0..15
        const int c4  = (t & 31) << 2;   // 0..124
        float4 v = *reinterpret_cast<const float4*>(fn + (size_t)(ib + row) * ND + c4);
        *reinterpret_cast<float4*>(&fi[row][c4]) = v;
    }

    int labi[MI];
#pragma unroll
    for (int ii = 0; ii < MI; ++ii)
        labi[ii] = labels[ib + tr * MI + ii];

    float expsum[MI] = {0.f, 0.f, 0.f, 0.f};
    float possum[MI] = {0.f, 0.f, 0.f, 0.f};
    float numpos[MI] = {0.f, 0.f, 0.f, 0.f};

    for (int jb = 0; jb < NB; jb += TJ) {
        float acc[MI][NJ] = {};
        for (int dc = 0; dc < ND; dc += DC) {
            __syncthreads();  // previous chunk's compute done before overwrite
            // stage fj[512][32]: 8 float4 per thread
            {
                const int rr = t >> 3;          // 0..63
                const int c4 = (t & 7) << 2;    // 0..28
#pragma unroll
                for (int p = 0; p < TJ / 64; ++p) {
                    const int row = rr + p * 64;
                    float4 v = *reinterpret_cast<const float4*>(
                        fn + (size_t)(jb + row) * ND + dc + c4);
                    *reinterpret_cast<float4*>(&fj[row][c4]) = v;
                }
            }
            __syncthreads();
            // compute: 8 c-iters x (8 ds_read_b128 + 64 FMA)
#pragma unroll
            for (int c = 0; c < DC; c += 4) {
                float4 a[MI], b[NJ];
#pragma unroll
                for (int ii = 0; ii < MI; ++ii)
                    a[ii] = *reinterpret_cast<const float4*>(&fi[tr * MI + ii][dc + c]);
#pragma unroll
                for (int jj = 0; jj < NJ; ++jj)
                    b[jj] = *reinterpret_cast<const float4*>(&fj[tc + 128 * jj][c]);
#pragma unroll
                for (int ii = 0; ii < MI; ++ii)
#pragma unroll
                    for (int jj = 0; jj < NJ; ++jj)
                        acc[ii][jj] += a[ii].x * b[jj].x + a[ii].y * b[jj].y
                                     + a[ii].z * b[jj].z + a[ii].w * b[jj].w;
            }
        }
        // fold tile sims into per-thread row stats
#pragma unroll
        for (int jj = 0; jj < NJ; ++jj) {
            const int jg   = jb + tc + 128 * jj;
            const int labj = labels[jg];
#pragma unroll
            for (int ii = 0; ii < MI; ++ii) {
                const int ig = ib + tr * MI + ii;
                const float s = acc[ii][jj];
                if (jg != ig) {
                    expsum[ii] += __expf(s);
                    if (labj == labi[ii]) { possum[ii] += s; numpos[ii] += 1.f; }
                }
            }
        }
    }

    // cross-lane reduce (each row's stats live in 128 threads = 2 waves)
#pragma unroll
    for (int off = 1; off < 64; off <<= 1) {
#pragma unroll
        for (int ii = 0; ii < MI; ++ii) {
            expsum[ii] += __shfl_xor(expsum[ii], off, 64);
            possum[ii] += __shfl_xor(possum[ii], off, 64);
            numpos[ii] += __shfl_xor(numpos[ii], off, 64);
        }
    }
    const int wave = t >> 6, lane = t & 63;
    if (lane == 0) {
#pragma unroll
        for (int ii = 0; ii < MI; ++ii) {
            red[wave][ii][0] = expsum[ii];
            red[wave][ii][1] = possum[ii];
            red[wave][ii][2] = numpos[ii];
        }
    }
    __syncthreads();
    if (t < TI) {                 // i_local = t
        const int w0 = (t >> 2) * 2;
        const int ii = t & 3;
        const float es = red[w0][ii][0] + red[w0 + 1][ii][0];
        const float ps = red[w0][ii][1] + red[w0 + 1][ii][1];
        const float np = red[w0][ii][2] + red[w0 + 1][ii][2];
        const float lse = logf(es);
        const float contrib = -(ps - np * lse) / ((np + 1e-5f) * (float)NB);
        atomicAdd(out, contrib);
    }
}

extern "C" void kernel_launch(void* const* d_in, const int* in_sizes, int n_in,
                              void* d_out, int out_size, void* d_ws, size_t ws_size,
                              hipStream_t stream) {
    const float* features = (const float*)d_in[0];
    const int*   labels   = (const int*)d_in[1];
    float* out   = (float*)d_out;
    float* fnorm = (float*)d_ws;  // 4096*128*4 = 2 MB

    hipMemsetAsync(d_out, 0, (size_t)out_size * sizeof(float), stream);
    rownorm_kernel<<<NB, 64, 0, stream>>>(features, fnorm);
    supcon_kernel<<<NB / TI, NTHREADS, 0, stream>>>(fnorm, labels, out);
}

// Round 2
// 39.904 us; speedup vs baseline: 5.3843x; 5.3843x over previous
//
#include <hip/hip_runtime.h>
#include <math.h>

#define NB 4096
#define ND 128
#define NCS 16        // column splits (blocks along j)
#define BI 64         // rows per block
#define BJ 256        // cols per block

typedef __bf16 bf16x8 __attribute__((ext_vector_type(8)));
typedef __bf16 bf16x2 __attribute__((ext_vector_type(2)));
typedef float  f32x4  __attribute__((ext_vector_type(4)));

// ---- pass 1: L2-normalize rows, emit bf16 ----------------------------------
__global__ void rownorm_kernel(const float* __restrict__ f, __bf16* __restrict__ fnb) {
    const int row  = blockIdx.x;
    const int lane = threadIdx.x;           // 64 lanes x 2 floats
    float2 v = reinterpret_cast<const float2*>(f + (size_t)row * ND)[lane];
    float ss = v.x * v.x + v.y * v.y;
#pragma unroll
    for (int off = 1; off < 64; off <<= 1) ss += __shfl_xor(ss, off, 64);
    const float inv = 1.0f / fmaxf(sqrtf(ss), 1e-12f);
    bf16x2 o; o[0] = (__bf16)(v.x * inv); o[1] = (__bf16)(v.y * inv);
    reinterpret_cast<bf16x2*>(fnb + (size_t)row * ND)[lane] = o;
}

// ---- pass 2: sim-GEMM via MFMA + fused online stats -------------------------
// grid: blockIdx.x = bi*NCS + cs ; block 256 thr = 4 waves (wr = wid>>1, wc = wid&1)
// wave tile: 32 rows x 128 cols; block tile: 64 x 256
__global__ __launch_bounds__(256) void supcon_mfma(
    const __bf16* __restrict__ fn, const int* __restrict__ labels,
    float* __restrict__ partials)
{
    __shared__ float redL[2][BI][3];
    const int t    = threadIdx.x;
    const int wid  = t >> 6, lane = t & 63;
    const int wr   = wid >> 1, wc = wid & 1;
    const int bi   = blockIdx.x >> 4;       // 0..63
    const int cs   = blockIdx.x & (NCS - 1);
    const int ib   = bi * BI + wr * 32;
    const int jb   = cs * BJ + wc * 128;
    const int lr   = lane & 15;             // row/col residue in 16-tile
    const int lk   = lane >> 4;             // k-group 0..3

    // preload A fragments for all 4 K-steps: a[it][ks], 16B contiguous per lane
    bf16x8 a[2][4];
#pragma unroll
    for (int it = 0; it < 2; ++it)
#pragma unroll
        for (int ks = 0; ks < 4; ++ks)
            a[it][ks] = *reinterpret_cast<const bf16x8*>(
                fn + (size_t)(ib + it * 16 + lr) * ND + ks * 32 + lk * 8);

    int labi[2][4];
#pragma unroll
    for (int it = 0; it < 2; ++it)
#pragma unroll
        for (int r = 0; r < 4; ++r)
            labi[it][r] = labels[ib + it * 16 + lk * 4 + r];

    float es[2][4] = {}, ps[2][4] = {}, np[2][4] = {};

#pragma unroll
    for (int jt = 0; jt < 8; ++jt) {
        bf16x8 b[4];
#pragma unroll
        for (int ks = 0; ks < 4; ++ks)
            b[ks] = *reinterpret_cast<const bf16x8*>(
                fn + (size_t)(jb + jt * 16 + lr) * ND + ks * 32 + lk * 8);
        f32x4 acc[2] = {};
#pragma unroll
        for (int ks = 0; ks < 4; ++ks) {
            acc[0] = __builtin_amdgcn_mfma_f32_16x16x32_bf16(a[0][ks], b[ks], acc[0], 0, 0, 0);
            acc[1] = __builtin_amdgcn_mfma_f32_16x16x32_bf16(a[1][ks], b[ks], acc[1], 0, 0, 0);
        }
        // fused epilogue: C/D layout col = lane&15, row = (lane>>4)*4 + r
        const int jg   = jb + jt * 16 + lr;
        const int labj = labels[jg];
#pragma unroll
        for (int it = 0; it < 2; ++it)
#pragma unroll
            for (int r = 0; r < 4; ++r) {
                const int   ig   = ib + it * 16 + lk * 4 + r;
                const float s    = acc[it][r];
                const float e    = __expf(s);
                const bool  self = (jg == ig);
                const bool  pos  = (labj == labi[it][r]) && !self;
                es[it][r] += self ? 0.f : e;
                ps[it][r] += pos ? s : 0.f;
                np[it][r] += pos ? 1.f : 0.f;
            }
    }

    // reduce across the 16 col-lanes (offsets 1,2,4,8 stay inside the group)
#pragma unroll
    for (int off = 1; off < 16; off <<= 1)
#pragma unroll
        for (int it = 0; it < 2; ++it)
#pragma unroll
            for (int r = 0; r < 4; ++r) {
                es[it][r] += __shfl_xor(es[it][r], off, 64);
                ps[it][r] += __shfl_xor(ps[it][r], off, 64);
                np[it][r] += __shfl_xor(np[it][r], off, 64);
            }
    if (lr == 0) {
#pragma unroll
        for (int it = 0; it < 2; ++it)
#pragma unroll
            for (int r = 0; r < 4; ++r) {
                const int rl = wr * 32 + it * 16 + lk * 4 + r;
                redL[wc][rl][0] = es[it][r];
                redL[wc][rl][1] = ps[it][r];
                redL[wc][rl][2] = np[it][r];
            }
    }
    __syncthreads();
    if (t < BI) {  // fold the two col-waves, one deterministic writer per (cs,row)
        float* p = partials + ((size_t)cs * NB + bi * BI + t) * 3;
        p[0] = redL[0][t][0] + redL[1][t][0];
        p[1] = redL[0][t][1] + redL[1][t][1];
        p[2] = redL[0][t][2] + redL[1][t][2];
    }
}

// ---- pass 3: per-row loss + global reduce ----------------------------------
__global__ void final_kernel(const float* __restrict__ partials, float* __restrict__ out) {
    const int row = blockIdx.x * 256 + threadIdx.x;
    float es = 0.f, ps = 0.f, np = 0.f;
#pragma unroll
    for (int cs = 0; cs < NCS; ++cs) {
        const float* p = partials + ((size_t)cs * NB + row) * 3;
        es += p[0]; ps += p[1]; np += p[2];
    }
    const float lse = logf(es);
    float c = -(ps - np * lse) / ((np + 1e-5f) * (float)NB);
#pragma unroll
    for (int off = 1; off < 64; off <<= 1) c += __shfl_xor(c, off, 64);
    __shared__ float sred[4];
    if ((threadIdx.x & 63) == 0) sred[threadIdx.x >> 6] = c;
    __syncthreads();
    if (threadIdx.x == 0) atomicAdd(out, sred[0] + sred[1] + sred[2] + sred[3]);
}

extern "C" void kernel_launch(void* const* d_in, const int* in_sizes, int n_in,
                              void* d_out, int out_size, void* d_ws, size_t ws_size,
                              hipStream_t stream) {
    const float* features = (const float*)d_in[0];
    const int*   labels   = (const int*)d_in[1];
    float* out = (float*)d_out;

    __bf16* fnb      = (__bf16*)d_ws;                         // 4096*128*2 = 1 MB
    float*  partials = (float*)((char*)d_ws + (size_t)NB * ND * 2);  // 16*4096*3*4 = 768 KB

    hipMemsetAsync(d_out, 0, (size_t)out_size * sizeof(float), stream);
    rownorm_kernel<<<NB, 64, 0, stream>>>(features, fnb);
    supcon_mfma<<<(NB / BI) * NCS, 256, 0, stream>>>(fnb, labels, partials);
    final_kernel<<<NB / 256, 256, 0, stream>>>(partials, out);
}